// Round 5
// baseline (1233.769 us; speedup 1.0000x reference)
//
#include <hip/hip_runtime.h>
#include <hip/hip_bf16.h>
#include <hip/hip_fp16.h>
#include <stdint.h>

// Problem: T=512, B=128, INPUT=256, HIDDEN=512
//   xp = einsum('tbi,hi->tbh', x, Wx) + b      (phase 1, parallel GEMM)
//   h_{t+1} = tanh(xp_t + h_t @ Wh^T)          (phase 2, 512 sequential steps)
//   out = [h0(=0); h1..h512]  fp32, shape (513,128,512)
//
// R8 (2nd resubmit; R3 broker timeout, R4 container failure — never
// measured): scan tail + regalloc rework vs R7 (scan 818us).
//  - part[] LDS reduce + 2nd barrier REMOVED: the 8 k-partials of row n
//    live in 8 consecutive lanes (tid = rb*8+ks); butterfly __shfl_xor
//    (1,2,4) reduces in-register, thread tid emits row tid.
//  - ONE barrier/step, race-free via double-buffered h (hA/hB, unroll x2).
//  - weights pinned as 192 SCALAR u32 (R7's 48 aligned "+v" quads pushed
//    the allocator to AGPRs -> VGPR_Count=128 + accvgpr round-trips).
//  - per-k-chunk software pipeline: LDS reads (h, w6, w7) issue first,
//    24 resident fdot2 cover the latency, then the 2 LDS-row dots.
#define T_STEPS 512
#define BATCH   128
#define NIN     256
#define HID     512

typedef _Float16 f16x2 __attribute__((ext_vector_type(2)));
typedef unsigned int u32x4 __attribute__((ext_vector_type(4)));

__device__ __forceinline__ float fdot2u(uint32_t a, uint32_t b, float c) {
#if __has_builtin(__builtin_amdgcn_fdot2)
  return __builtin_amdgcn_fdot2(__builtin_bit_cast(f16x2, a),
                                __builtin_bit_cast(f16x2, b), c, false);
#else
  __half2 ha = __builtin_bit_cast(__half2, a);
  __half2 hb = __builtin_bit_cast(__half2, b);
  return c + __half2float(ha.x) * __half2float(hb.x)
           + __half2float(ha.y) * __half2float(hb.y);
#endif
}

__device__ __forceinline__ float dot8v(u32x4 w, u32x4 x, float a) {
  a = fdot2u(w.x, x.x, a);
  a = fdot2u(w.y, x.y, a);
  a = fdot2u(w.z, x.z, a);
  a = fdot2u(w.w, x.w, a);
  return a;
}

__device__ __forceinline__ float dot8(uint4 w, uint4 x, float a) {
  a = fdot2u(w.x, x.x, a);
  a = fdot2u(w.y, x.y, a);
  a = fdot2u(w.z, x.z, a);
  a = fdot2u(w.w, x.w, a);
  return a;
}

// ------------- phase 0: split + convert W (fp32[512][768]) to f16 -----------
__global__ void prep_w(const float* __restrict__ W,
                       __half* __restrict__ Wx, __half* __restrict__ Wh) {
  int idx = blockIdx.x * 256 + threadIdx.x;   // exactly 512*768 threads
  int h = idx / (NIN + HID);
  int c = idx - h * (NIN + HID);
  float v = W[idx];
  if (c < NIN) Wx[h * NIN + c] = __float2half(v);
  else         Wh[h * HID + (c - NIN)] = __float2half(v);
}

// ---------------- phase 1: xp[m][n] = sum_k x[m][k]*Wx[n][k] + b[n] ----------
__launch_bounds__(256)
__global__ void gemm_xp(const float* __restrict__ x,
                        const __half* __restrict__ Wx,
                        const float* __restrict__ bias,
                        float* __restrict__ xp) {
  __shared__ __align__(16) __half xs[32][256];

  const int bid = blockIdx.x;
  const int m0 = (bid >> 1) * 32;
  const int n0 = (bid & 1) * 256;
  const int tid = threadIdx.x;

  {
    int r = tid >> 3, cb = (tid & 7) * 32;
    const float* src = x + (size_t)(m0 + r) * NIN + cb;
    union { __half h[8]; uint4 u; } cv;
#pragma unroll
    for (int i = 0; i < 4; ++i) {
      float4 f0 = *(const float4*)(src + i * 8);
      float4 f1 = *(const float4*)(src + i * 8 + 4);
      cv.h[0] = __float2half(f0.x); cv.h[1] = __float2half(f0.y);
      cv.h[2] = __float2half(f0.z); cv.h[3] = __float2half(f0.w);
      cv.h[4] = __float2half(f1.x); cv.h[5] = __float2half(f1.y);
      cv.h[6] = __float2half(f1.z); cv.h[7] = __float2half(f1.w);
      *(uint4*)(void*)&xs[r][cb + i * 8] = cv.u;
    }
  }
  __syncthreads();

  const int rg = tid >> 6;
  const int c0 = tid & 63;

  float acc[8][4];
#pragma unroll
  for (int r = 0; r < 8; ++r)
#pragma unroll
    for (int j = 0; j < 4; ++j) acc[r][j] = 0.f;

  for (int kc = 0; kc < NIN; kc += 32) {
    uint4 w[4][4];
#pragma unroll
    for (int j = 0; j < 4; ++j) {
      const __half* wp = Wx + (size_t)(n0 + c0 + 64 * j) * NIN + kc;
#pragma unroll
      for (int i = 0; i < 4; ++i) w[j][i] = *(const uint4*)(wp + i * 8);
    }
#pragma unroll
    for (int r = 0; r < 8; ++r) {
      uint4 xv[4];
#pragma unroll
      for (int i = 0; i < 4; ++i)
        xv[i] = *(const uint4*)(const void*)&xs[rg * 8 + r][kc + i * 8];
#pragma unroll
      for (int j = 0; j < 4; ++j)
#pragma unroll
        for (int i = 0; i < 4; ++i) acc[r][j] = dot8(w[j][i], xv[i], acc[r][j]);
    }
  }

  float bj[4];
#pragma unroll
  for (int j = 0; j < 4; ++j) bj[j] = bias[n0 + c0 + 64 * j];
#pragma unroll
  for (int r = 0; r < 8; ++r) {
    float* dst = xp + (size_t)(m0 + rg * 8 + r) * HID + n0 + c0;
#pragma unroll
    for (int j = 0; j < 4; ++j) dst[64 * j] = acc[r][j] + bj[j];
  }
}

// ---------------- phase 2: sequential scan, one WG (512 thr) per batch -------
// Thread (rb = tid>>3, ks = tid&7) owns rows rb*8..rb*8+7, k in [ks*64,+64).
// Rows 0..5: 192 scalar-u32 VGPR-resident (pinned). Rows 6..7: LDS, 128 KB,
// staged once, XOR-swizzled (slot = i^ks). h double-buffered in LDS at
// 72-half chunk stride. In-wave butterfly reduce (shfl_xor 1/2/4) -> thread
// tid emits row tid. ONE barrier per step. xp_{t+1} prefetched each step.
// io block t+1 holds xp_t (fp32), overwritten in place by h_{t+1}.
#define HCH 72   // h chunk stride in halves (144 B -> bank rot 4/chunk)
__launch_bounds__(512, 2)
__global__ void rnn_scan(const __half* __restrict__ Wh, float* io) {
  __shared__ __align__(16) char   whl[131072];      // rows 6,7 of each rb
  __shared__ __align__(16) __half hA[8 * HCH];      // h ping
  __shared__ __align__(16) __half hB[8 * HCH];      // h pong  (tot ~130 KiB)

  const int b   = blockIdx.x;
  const int tid = threadIdx.x;
  const int ks  = tid & 7;
  const int rb  = tid >> 3;
  const int R0  = rb * 8;
  const __half* wbase = Wh + (size_t)R0 * HID + ks * 64;

  // rows 0..5 resident as 192 scalar u32 (easier to color than quads)
  uint32_t wres[6][32];
#pragma unroll
  for (int r = 0; r < 6; ++r)
#pragma unroll
    for (int i = 0; i < 8; ++i) {
      u32x4 q = *(const u32x4*)(const void*)(wbase + (size_t)r * HID + i * 8);
      wres[r][4 * i + 0] = q.x; wres[r][4 * i + 1] = q.y;
      wres[r][4 * i + 2] = q.z; wres[r][4 * i + 3] = q.w;
    }
#pragma unroll
  for (int r = 0; r < 6; ++r)
#pragma unroll
    for (int j = 0; j < 32; ++j)
      asm volatile("" : "+v"(wres[r][j]));

  // stage rows 6,7 into LDS, XOR-swizzled: logical chunk elem i at slot i^ks
  const int off6 = (((rb * 2) * 8 + ks) << 7) | (ks << 4);
#pragma unroll
  for (int i = 0; i < 8; ++i) {
    u32x4 v6 = *(const u32x4*)(const void*)(wbase + (size_t)6 * HID + i * 8);
    u32x4 v7 = *(const u32x4*)(const void*)(wbase + (size_t)7 * HID + i * 8);
    *(u32x4*)(void*)(whl + (off6 ^ (i << 4)))          = v6;
    *(u32x4*)(void*)(whl + ((off6 ^ (i << 4)) + 1024)) = v7;
  }

  // h0 = 0 (into hA); emit output block t=0
  const int hwb = (tid >> 6) * HCH + (tid & 63);
  hA[hwb] = __float2half(0.f);
  io[(size_t)b * HID + tid] = 0.f;
  __syncthreads();

  float* iorow = io + (size_t)BATCH * HID + (size_t)b * HID + tid;
  float xpv = *iorow;                    // xp_0

  auto do_step = [&](const __half* rd, __half* wr, float xpi, float* iop,
                     int t) -> float {
    // prefetch next step's xp — dots below hide the HBM latency
    float xpn = 0.f;
    if (t + 1 < T_STEPS) xpn = iop[BATCH * HID];

    float acc[8];
#pragma unroll
    for (int r = 0; r < 8; ++r) acc[r] = 0.f;

#pragma unroll
    for (int i = 0; i < 8; ++i) {
      u32x4 hj = *(const u32x4*)(const void*)((const char*)rd + ks * 144 + i * 16);
      u32x4 w6 = *(const u32x4*)(const void*)(whl + (off6 ^ (i << 4)));
      u32x4 w7 = *(const u32x4*)(const void*)(whl + ((off6 ^ (i << 4)) + 1024));
#pragma unroll
      for (int r = 0; r < 6; ++r) {
        acc[r] = fdot2u(wres[r][4 * i + 0], hj.x, acc[r]);
        acc[r] = fdot2u(wres[r][4 * i + 1], hj.y, acc[r]);
        acc[r] = fdot2u(wres[r][4 * i + 2], hj.z, acc[r]);
        acc[r] = fdot2u(wres[r][4 * i + 3], hj.w, acc[r]);
      }
      acc[6] = dot8v(w6, hj, acc[6]);
      acc[7] = dot8v(w7, hj, acc[7]);
    }

    // butterfly over the 8 ks lanes (consecutive lanes within the wave)
    float sum[8];
#pragma unroll
    for (int r = 0; r < 8; ++r) {
      float v = acc[r];
      v += __shfl_xor(v, 1);
      v += __shfl_xor(v, 2);
      v += __shfl_xor(v, 4);
      sum[r] = v;
    }
    float s = sum[0];
#pragma unroll
    for (int r = 1; r < 8; ++r) s = (ks == r) ? sum[r] : s;

    s += xpi;                            // xp_t (prefetched)
    float e  = __expf(fminf(fmaxf(2.f * s, -40.f), 40.f));
    float hn = (e - 1.f) / (e + 1.f);
    *iop = hn;                           // h_{t+1} overwrites xp_t in place
    wr[hwb] = __float2half(hn);
    __syncthreads();
    return xpn;
  };

  for (int t = 0; t < T_STEPS; t += 2) {
    xpv = do_step(hA, hB, xpv, iorow, t);
    iorow += BATCH * HID;
    xpv = do_step(hB, hA, xpv, iorow, t + 1);
    iorow += BATCH * HID;
  }
}

extern "C" void kernel_launch(void* const* d_in, const int* in_sizes, int n_in,
                              void* d_out, int out_size, void* d_ws, size_t ws_size,
                              hipStream_t stream) {
  const float* x    = (const float*)d_in[0];   // (512,128,256) fp32
  const float* W    = (const float*)d_in[1];   // (512,768) fp32
  const float* bias = (const float*)d_in[2];   // (512,) fp32

  char* ws = (char*)d_ws;
  __half* Wx = (__half*)ws;                    // 512*256*2 = 256 KiB
  __half* Wh = (__half*)(ws + 262144);         // 512*512*2 = 512 KiB

  float* io = (float*)d_out;
  float* xp = io + (size_t)BATCH * HID;

  prep_w<<<1536, 256, 0, stream>>>(W, Wx, Wh);
  gemm_xp<<<4096, 256, 0, stream>>>(x, Wx, bias, xp);
  rnn_scan<<<BATCH, 512, 0, stream>>>(Wh, io);
}